// Round 9
// baseline (187.056 us; speedup 1.0000x reference)
//
#include <hip/hip_runtime.h>

#define DD 128
#define NNODES 50000
#define NEDGES 800000
#define BN_EPS 1e-5f
#define NB1 ((NEDGES + 4095) / 4096)       // 196 edge-slice blocks
#define NGROUPS ((NNODES + 255) / 256)     // 196 row-groups (256 rows each)

typedef float f32x4 __attribute__((ext_vector_type(4)));
typedef short bf16x8 __attribute__((ext_vector_type(8)));

__device__ __forceinline__ unsigned short f2bf(float f) {
    unsigned u = __float_as_uint(f);
    u = (u + 0x7FFFu + ((u >> 16) & 1u)) >> 16;   // RNE
    return (unsigned short)u;
}
__device__ __forceinline__ float bf2f(unsigned short s) {
    return __uint_as_float((unsigned)s << 16);
}
__device__ __forceinline__ unsigned packbf(float a, float b) {
    return (unsigned)f2bf(a) | ((unsigned)f2bf(b) << 16);
}
__device__ __forceinline__ float lo_bf(unsigned u) { return __uint_as_float(u << 16); }
__device__ __forceinline__ float hi_bf(unsigned u) { return __uint_as_float(u & 0xFFFF0000u); }

// async global->LDS, 16B per lane; LDS dest = wave-uniform base + lane*16
__device__ __forceinline__ void gload_lds16(const void* g, void* l) {
    __builtin_amdgcn_global_load_lds(
        (const __attribute__((address_space(1))) unsigned int*)g,
        (__attribute__((address_space(3))) unsigned int*)l, 16, 0, 0);
}

// ---------------------------------------------------------------------------
// K1: per-block LDS bucket histogram -> ONE global atomicAdd per (block,
// bucket) into bktcnt[256] (1KB, contention-free) + x->bf16 convert.
// ---------------------------------------------------------------------------
__global__ __launch_bounds__(256) void count_convx_kernel(
    const int* __restrict__ row, int* __restrict__ bktcnt,
    const float* __restrict__ x, unsigned* __restrict__ h16u,
    int nedges, int npairs)
{
    const int bid = blockIdx.x;
    if (bid < NB1) {
        __shared__ int cnt[256];
        cnt[threadIdx.x] = 0;
        __syncthreads();
        const int estart = bid * 4096;
        const int eend = min(estart + 4096, nedges);
        for (int e = estart + threadIdx.x; e < eend; e += 256)
            atomicAdd(&cnt[row[e] >> 8], 1);          // LDS atomic
        __syncthreads();
        if (cnt[threadIdx.x]) atomicAdd(&bktcnt[threadIdx.x], cnt[threadIdx.x]);
    } else {
        int stride = (gridDim.x - NB1) * 256;
        for (int i = (bid - NB1) * 256 + threadIdx.x; i < npairs; i += stride) {
            float2 v = ((const float2*)x)[i];
            h16u[i] = packbf(v.x, v.y);
        }
    }
}

// ---------------------------------------------------------------------------
// K2: block 0: LDS-scan bktcnt -> bktbase[257] + bcur init; rowptr[N]=NEDGES.
// Blocks 1..48: weight->fragment convert.
// Wf: [li][ks][nt][lane][i] bf16; value = B[k][n],
//     k = ks*32+(lane>>4)*8+i (k<128 -> W else SW), n = nt*16+(lane&15)
// ---------------------------------------------------------------------------
__global__ __launch_bounds__(256) void scanall_convwf_kernel(
    const int* __restrict__ bktcnt, int* __restrict__ bktbase,
    int* __restrict__ bcur, int* __restrict__ rowptr,
    const float* __restrict__ W, const float* __restrict__ SW,
    unsigned short* __restrict__ Wf)
{
    if (blockIdx.x == 0) {
        __shared__ int buf[256];
        const int t = threadIdx.x;
        const int v = bktcnt[t];
        buf[t] = v;
        __syncthreads();
#pragma unroll
        for (int off = 1; off < 256; off <<= 1) {
            int tv = (t >= off) ? buf[t - off] : 0;
            __syncthreads();
            buf[t] += tv;
            __syncthreads();
        }
        const int excl = buf[t] - v;
        bktbase[t] = excl;
        bcur[t] = excl;
        if (t == 255) bktbase[256] = buf[255];
        if (t == 0) rowptr[NNODES] = NEDGES;
        return;
    }
    int t = (blockIdx.x - 1) * 256 + threadIdx.x;   // 12288 total
    if (t < 3 * 8 * 8 * 64) {
        int lane = t & 63;
        int nt   = (t >> 6) & 7;
        int ks   = (t >> 9) & 7;
        int li   = t >> 12;
        const int lmap[3] = {0, 2, 5};
        int l = lmap[li];
        int nn = nt * 16 + (lane & 15);
        unsigned short* dst = Wf + (((size_t)li * 64 + ks * 8 + nt) * 64 + lane) * 8;
#pragma unroll
        for (int i = 0; i < 8; ++i) {
            int k = ks * 32 + (lane >> 4) * 8 + i;
            float v = (k < 128) ? W[((size_t)l * 128 + k) * 128 + nn]
                                : SW[((size_t)l * 128 + (k - 128)) * 128 + nn];
            dst[i] = f2bf(v);
        }
    }
}

// ---------------------------------------------------------------------------
// K3: bin edges into contiguous per-bucket streams. Range reserved with one
// global atomic per (block,bucket); rank from LDS counters.
// Record: {payload = col | w_bf16<<16, rlow = row & 255} (8B).
// ---------------------------------------------------------------------------
__global__ __launch_bounds__(256) void sort_pass1_kernel(
    const int* __restrict__ row, const int* __restrict__ col,
    const float* __restrict__ ew, int* __restrict__ bcur,
    uint2* __restrict__ inter, int nedges)
{
    __shared__ int cnt[256];
    __shared__ int base[256];
    cnt[threadIdx.x] = 0;
    __syncthreads();
    const int estart = blockIdx.x * 4096;
    const int eend = min(estart + 4096, nedges);
    for (int e = estart + threadIdx.x; e < eend; e += 256)
        atomicAdd(&cnt[row[e] >> 8], 1);              // LDS atomic
    __syncthreads();
    base[threadIdx.x] = cnt[threadIdx.x]
        ? atomicAdd(&bcur[threadIdx.x], cnt[threadIdx.x]) : 0;
    __syncthreads();
    cnt[threadIdx.x] = 0;   // reuse as rank
    __syncthreads();
    for (int e = estart + threadIdx.x; e < eend; e += 256) {
        int r = row[e];
        int b = r >> 8;
        int k = atomicAdd(&cnt[b], 1);                // LDS atomic
        unsigned payload = (unsigned)col[e] | ((unsigned)f2bf(ew[e]) << 16);
        inter[base[b] + k] = make_uint2(payload, (unsigned)(r & 255));
    }
}

// ---------------------------------------------------------------------------
// K4: one block per 256-row group. LDS-hist rlow -> LDS scan -> rowptr for
// this group; then windowed scatter into the group's 16KB cedge slice.
// ---------------------------------------------------------------------------
__global__ __launch_bounds__(256) void sort_pass2_kernel(
    const int* __restrict__ bktbase, const uint2* __restrict__ inter,
    int* __restrict__ rowptr, unsigned* __restrict__ cedge, int n)
{
    __shared__ int cnt[256];
    __shared__ int cur[256];
    const int g = blockIdx.x;
    const int rows0 = g * 256;
    const int jbeg = bktbase[g];
    const int jend = bktbase[g + 1];
    cnt[threadIdx.x] = 0;
    __syncthreads();
    for (int j = jbeg + threadIdx.x; j < jend; j += 256)
        atomicAdd(&cnt[inter[j].y], 1);   // LDS atomic
    __syncthreads();
    const int v = cnt[threadIdx.x];
    __syncthreads();
#pragma unroll
    for (int off = 1; off < 256; off <<= 1) {
        int t = (threadIdx.x >= off) ? cnt[threadIdx.x - off] : 0;
        __syncthreads();
        cnt[threadIdx.x] += t;
        __syncthreads();
    }
    const int rp = jbeg + cnt[threadIdx.x] - v;   // exclusive prefix
    if (rows0 + threadIdx.x < n) rowptr[rows0 + threadIdx.x] = rp;
    cur[threadIdx.x] = rp;
    __syncthreads();
    for (int j = jbeg + threadIdx.x; j < jend; j += 256) {
        uint2 rec = inter[j];
        int p = atomicAdd(&cur[rec.y], 1);        // LDS atomic
        cedge[p] = rec.x;
    }
}

// ---------------------------------------------------------------------------
// CSR gather: one wave per node; FOUR 16-lane quarters each walk every 4th
// edge. Lane owns 8 bf16 cols (uint4) -> quarter covers the 256B row; x4
// unroll -> 16 row-reads in flight/wave. Combine via shfl_xor(16,32).
// ---------------------------------------------------------------------------
__global__ __launch_bounds__(256) void spmm_gather16_kernel(
    const uint4* __restrict__ h4, const int* __restrict__ rowptr,
    const unsigned* __restrict__ ce, uint4* __restrict__ agg4, int n)
{
    int node = blockIdx.x * 4 + (threadIdx.x >> 6);
    if (node >= n) return;
    const int lane = threadIdx.x & 63;
    const int q    = lane >> 4;          // quarter 0..3
    const int l16  = lane & 15;
    const int beg = rowptr[node];
    const int end = rowptr[node + 1];

    float a0 = 0.f, a1 = 0.f, a2 = 0.f, a3 = 0.f;
    float a4 = 0.f, a5 = 0.f, a6 = 0.f, a7 = 0.f;

    int j = beg + q;
    for (; j + 12 < end; j += 16) {
        unsigned e0 = ce[j], e1 = ce[j+4], e2 = ce[j+8], e3 = ce[j+12];
        uint4 v0 = h4[(size_t)(e0 & 0xFFFFu) * 16 + l16];
        uint4 v1 = h4[(size_t)(e1 & 0xFFFFu) * 16 + l16];
        uint4 v2 = h4[(size_t)(e2 & 0xFFFFu) * 16 + l16];
        uint4 v3 = h4[(size_t)(e3 & 0xFFFFu) * 16 + l16];
        float w0 = bf2f((unsigned short)(e0 >> 16));
        float w1 = bf2f((unsigned short)(e1 >> 16));
        float w2 = bf2f((unsigned short)(e2 >> 16));
        float w3 = bf2f((unsigned short)(e3 >> 16));
        a0 += w0*lo_bf(v0.x) + w1*lo_bf(v1.x) + w2*lo_bf(v2.x) + w3*lo_bf(v3.x);
        a1 += w0*hi_bf(v0.x) + w1*hi_bf(v1.x) + w2*hi_bf(v2.x) + w3*hi_bf(v3.x);
        a2 += w0*lo_bf(v0.y) + w1*lo_bf(v1.y) + w2*lo_bf(v2.y) + w3*lo_bf(v3.y);
        a3 += w0*hi_bf(v0.y) + w1*hi_bf(v1.y) + w2*hi_bf(v2.y) + w3*hi_bf(v3.y);
        a4 += w0*lo_bf(v0.z) + w1*lo_bf(v1.z) + w2*lo_bf(v2.z) + w3*lo_bf(v3.z);
        a5 += w0*hi_bf(v0.z) + w1*hi_bf(v1.z) + w2*hi_bf(v2.z) + w3*hi_bf(v3.z);
        a6 += w0*lo_bf(v0.w) + w1*lo_bf(v1.w) + w2*lo_bf(v2.w) + w3*lo_bf(v3.w);
        a7 += w0*hi_bf(v0.w) + w1*hi_bf(v1.w) + w2*hi_bf(v2.w) + w3*hi_bf(v3.w);
    }
    for (; j < end; j += 4) {
        unsigned e = ce[j];
        uint4 v = h4[(size_t)(e & 0xFFFFu) * 16 + l16];
        float w = bf2f((unsigned short)(e >> 16));
        a0 += w * lo_bf(v.x); a1 += w * hi_bf(v.x);
        a2 += w * lo_bf(v.y); a3 += w * hi_bf(v.y);
        a4 += w * lo_bf(v.z); a5 += w * hi_bf(v.z);
        a6 += w * lo_bf(v.w); a7 += w * hi_bf(v.w);
    }
#pragma unroll
    for (int off = 16; off <= 32; off <<= 1) {
        a0 += __shfl_xor(a0, off); a1 += __shfl_xor(a1, off);
        a2 += __shfl_xor(a2, off); a3 += __shfl_xor(a3, off);
        a4 += __shfl_xor(a4, off); a5 += __shfl_xor(a5, off);
        a6 += __shfl_xor(a6, off); a7 += __shfl_xor(a7, off);
    }
    if (q == 0)
        agg4[(size_t)node * 16 + l16] =
            make_uint4(packbf(a0, a1), packbf(a2, a3), packbf(a4, a5), packbf(a6, a7));
}

// ---------------------------------------------------------------------------
// MFMA GEMM: C = [agg|h](N x 256) @ [W;SW](256 x 128), then BN+relu+residual.
// A-tile staged via async global_load_lds (16B/lane): LINEAR LDS dest,
// INVERSE-swizzled global source (chunk kc^(r&7) within the row), swizzled
// ds_read on consume -- rule: swizzle both sides or neither (m173 pattern).
// Last layer writes only f32 out.
// ---------------------------------------------------------------------------
__global__ __launch_bounds__(256) void gemm_mfma_kernel(
    unsigned short* __restrict__ h16,
    const unsigned short* __restrict__ agg16,
    const unsigned short* __restrict__ Wf,
    const float* __restrict__ bl, const float* __restrict__ gammal,
    const float* __restrict__ betal, const float* __restrict__ rmeanl,
    const float* __restrict__ rvarl,
    float* __restrict__ outf, int n, int write_f32)
{
    __shared__ __align__(16) unsigned short As[64 * 256];   // 32 KB
    const int tid   = threadIdx.x;
    const int lane  = tid & 63;
    const int wid   = tid >> 6;
    const int wbase = tid & 192;        // wave-uniform: wid*64
    const int brow  = blockIdx.x * 64;

    // ---- stage A tile: async direct-to-LDS, 8 x 1KB per wave ----
#pragma unroll
    for (int it = 0; it < 8; ++it) {
        const int base_id = it * 256 + wbase;     // wave-uniform LDS slot base
        const int id  = base_id + lane;
        const int r   = id >> 5;
        const int kc  = id & 31;
        const int kcg = kc ^ (r & 7);             // inverse swizzle on SOURCE
        const int grow = brow + r;
        const unsigned short* src = (kcg < 16)
            ? (agg16 + (size_t)grow * DD + kcg * 8)
            : (h16   + (size_t)grow * DD + (kcg - 16) * 8);
        if (grow < n)
            gload_lds16(src, &As[base_id * 8]);   // lane writes base + lane*16
    }

    // ---- B prefetch (overlaps the async LDS fill) ----
    bf16x8 bfr[8][2];
#pragma unroll
    for (int ks = 0; ks < 8; ++ks)
#pragma unroll
        for (int nt2 = 0; nt2 < 2; ++nt2) {
            int nt = wid * 2 + nt2;
            bfr[ks][nt2] = *(const bf16x8*)(Wf + ((size_t)(ks * 8 + nt) * 64 + lane) * 8);
        }
    __syncthreads();

    f32x4 acc[4][2];
#pragma unroll
    for (int i = 0; i < 4; ++i)
#pragma unroll
        for (int j = 0; j < 2; ++j)
            acc[i][j] = (f32x4){0.f, 0.f, 0.f, 0.f};

#pragma unroll
    for (int ks = 0; ks < 8; ++ks) {
#pragma unroll
        for (int mt = 0; mt < 4; ++mt) {
            int m   = mt * 16 + (lane & 15);
            int kc  = ks * 4 + (lane >> 4);
            int kcs = kc ^ (m & 7);
            bf16x8 afr = *(const bf16x8*)(&As[m * 256 + kcs * 8]);
            acc[mt][0] = __builtin_amdgcn_mfma_f32_16x16x32_bf16(afr, bfr[ks][0], acc[mt][0], 0, 0, 0);
            acc[mt][1] = __builtin_amdgcn_mfma_f32_16x16x32_bf16(afr, bfr[ks][1], acc[mt][1], 0, 0, 0);
        }
    }

#pragma unroll
    for (int nt2 = 0; nt2 < 2; ++nt2) {
        const int gcol = wid * 32 + nt2 * 16 + (lane & 15);
        const float sc = gammal[gcol] * __frsqrt_rn(rvarl[gcol] + BN_EPS);
        const float sh = (bl[gcol] - rmeanl[gcol]) * sc + betal[gcol];
        const int kc_res = 16 + (gcol >> 3);
        const int ko_res = gcol & 7;
#pragma unroll
        for (int mt = 0; mt < 4; ++mt) {
#pragma unroll
            for (int r = 0; r < 4; ++r) {
                int m = mt * 16 + (lane >> 4) * 4 + r;
                int grow = brow + m;
                if (grow < n) {
                    float res = bf2f(As[m * 256 + (kc_res ^ (m & 7)) * 8 + ko_res]);
                    float t = acc[mt][nt2][r] * sc + sh;
                    float o = res + (t > 0.f ? t : 0.f);
                    if (write_f32) outf[(size_t)grow * DD + gcol] = o;
                    else           h16[(size_t)grow * DD + gcol] = f2bf(o);
                }
            }
        }
    }
}

extern "C" void kernel_launch(void* const* d_in, const int* in_sizes, int n_in,
                              void* d_out, int out_size, void* d_ws, size_t ws_size,
                              hipStream_t stream) {
    const float* x     = (const float*)d_in[0];
    const int*   row   = (const int*)  d_in[1];
    const int*   col   = (const int*)  d_in[2];
    const float* ew    = (const float*)d_in[3];
    const float* W     = (const float*)d_in[4];
    const float* SW    = (const float*)d_in[5];
    const float* b     = (const float*)d_in[6];
    const float* gamma = (const float*)d_in[7];
    const float* beta  = (const float*)d_in[8];
    const float* rmean = (const float*)d_in[9];
    const float* rvar  = (const float*)d_in[10];

    float* out = (float*)d_out;

    // workspace layout
    char* ws = (char*)d_ws;
    unsigned*       agg16u = (unsigned*)ws;                       // 12.8 MB
    unsigned*       h16u   = (unsigned*)(ws + 12800000);          // 12.8 MB
    unsigned short* Wf     = (unsigned short*)(ws + 25600000);    // 196608 B
    int*   rowptr  = (int*)(ws + 25800000);                       // 50001 ints
    int*   bktcnt  = (int*)(ws + 26010000);                       // 256
    int*   bktbase = (int*)(ws + 26011024);                       // 257
    int*   bcur    = (int*)(ws + 26012064);                       // 256
    unsigned* cedge = (unsigned*)(ws + 26400000);                 // 3.2 MB
    uint2*    inter = (uint2*)(ws + 29600000);                    // 6.4 MB

    // ---- build CSR (global atomics only on 256 bucket counters) ----
    hipMemsetAsync(bktcnt, 0, 256 * sizeof(int), stream);
    count_convx_kernel<<<NB1 + 2048, 256, 0, stream>>>(
        row, bktcnt, x, h16u, NEDGES, NNODES * 64);
    scanall_convwf_kernel<<<1 + 48, 256, 0, stream>>>(
        bktcnt, bktbase, bcur, rowptr, W, SW, Wf);
    sort_pass1_kernel<<<NB1, 256, 0, stream>>>(
        row, col, ew, bcur, inter, NEDGES);
    sort_pass2_kernel<<<NGROUPS, 256, 0, stream>>>(
        bktbase, inter, rowptr, cedge, NNODES);

    // Only layers 0, 2, 5 are live (inner branch layers all consume the
    // branch input, so only each branch's last layer reaches the output).
    const int ggrid = (NNODES + 3) / 4;       // 12500
    const int mgrid = (NNODES + 63) / 64;     // 782

    for (int li = 0; li < 3; ++li) {
        const int l = (li == 0) ? 0 : (li == 1) ? 2 : 5;
        spmm_gather16_kernel<<<ggrid, 256, 0, stream>>>(
            (const uint4*)h16u, rowptr, cedge, (uint4*)agg16u, NNODES);
        gemm_mfma_kernel<<<mgrid, 256, 0, stream>>>(
            (unsigned short*)h16u, (const unsigned short*)agg16u,
            Wf + (size_t)li * 32768,
            b + l * DD, gamma + l * DD, beta + l * DD, rmean + l * DD, rvar + l * DD,
            out, NNODES, li == 2 ? 1 : 0);
    }
}